// Round 4
// baseline (883.743 us; speedup 1.0000x reference)
//
#include <hip/hip_runtime.h>

#define DIM 64
#define RPB 128          // rows per bucket
#define NBLK1 512        // blocks for hist / bin-scatter (multiple of 8)

__device__ __forceinline__ float readlane_f(float v, int l) {
  return __uint_as_float(__builtin_amdgcn_readlane(__float_as_uint(v), l));
}

// ===========================================================================
// Fallback path (tiny workspace): atomic scatter + fused linear/LN/ReLU
// ===========================================================================
__global__ __launch_bounds__(256) void scatter_kernel(
    const float* __restrict__ x, const int* __restrict__ erow,
    const int* __restrict__ ecol, const float* __restrict__ eval,
    float* __restrict__ agg, int E) {
  int t = blockIdx.x * 256 + threadIdx.x;
  int e = t >> 4;
  if (e >= E) return;
  int lid = t & 15;
  int r = erow[e];
  int c = ecol[e];
  float v = eval[e];
  const float4 xv =
      *reinterpret_cast<const float4*>(x + (size_t)c * DIM + lid * 4);
  float* dst = agg + (size_t)r * DIM + lid * 4;
  atomicAdd(dst + 0, v * xv.x);
  atomicAdd(dst + 1, v * xv.y);
  atomicAdd(dst + 2, v * xv.z);
  atomicAdd(dst + 3, v * xv.w);
}

__global__ __launch_bounds__(256) void fused_linear_ln_relu(
    const float* __restrict__ agg, const float* __restrict__ W,
    const float* __restrict__ bias, const float* __restrict__ gamma,
    const float* __restrict__ beta, float* __restrict__ out, int N) {
  __shared__ float Wt[64 * 65];
  for (int i = threadIdx.x; i < 64 * 64; i += 256) {
    int d = i >> 6, k = i & 63;
    Wt[k * 65 + d] = W[i];
  }
  __syncthreads();

  const int wave = threadIdx.x >> 6;
  const int lane = threadIdx.x & 63;
  const int node0 = blockIdx.x * 16 + wave * 4;

  float a0 = 0.f, a1 = 0.f, a2 = 0.f, a3 = 0.f;
  if (node0 + 0 < N) a0 = agg[(size_t)(node0 + 0) * DIM + lane];
  if (node0 + 1 < N) a1 = agg[(size_t)(node0 + 1) * DIM + lane];
  if (node0 + 2 < N) a2 = agg[(size_t)(node0 + 2) * DIM + lane];
  if (node0 + 3 < N) a3 = agg[(size_t)(node0 + 3) * DIM + lane];

  float acc0 = 0.f, acc1 = 0.f, acc2 = 0.f, acc3 = 0.f;
#pragma unroll
  for (int k = 0; k < 64; ++k) {
    float w = Wt[k * 65 + lane];
    acc0 = fmaf(readlane_f(a0, k), w, acc0);
    acc1 = fmaf(readlane_f(a1, k), w, acc1);
    acc2 = fmaf(readlane_f(a2, k), w, acc2);
    acc3 = fmaf(readlane_f(a3, k), w, acc3);
  }

  const float bv = bias[lane];
  const float gv = gamma[lane];
  const float btv = beta[lane];
  float accs[4] = {acc0, acc1, acc2, acc3};
#pragma unroll
  for (int j = 0; j < 4; ++j) {
    int node = node0 + j;
    if (node >= N) continue;
    float h = accs[j] + bv;
    float s1 = h, s2 = h * h;
#pragma unroll
    for (int off = 32; off; off >>= 1) {
      s1 += __shfl_xor(s1, off, 64);
      s2 += __shfl_xor(s2, off, 64);
    }
    float mu = s1 * (1.0f / 64.0f);
    float var = s2 * (1.0f / 64.0f) - mu * mu;
    float inv = rsqrtf(var + 1e-5f);
    float y = (h - mu) * inv * gv + btv;
    out[(size_t)node * DIM + lane] = fmaxf(y, 0.0f);
  }
}

// ===========================================================================
// Bucketed path
// ===========================================================================

// 1) histogram into cnt[bucket*8 + (blockIdx&7)]
__global__ __launch_bounds__(256) void hist_bucket_kernel(
    const int* __restrict__ erow, int* __restrict__ cnt, int E, int cpb) {
  int b = blockIdx.x;
  int xp = b & 7;
  int base = b * cpb;
  int end = min(E, base + cpb);
  for (int e = base + threadIdx.x; e < end; e += 256) {
    int r = erow[e];
    atomicAdd(&cnt[(r >> 7) * 8 + xp], 1);
  }
}

// 2a) per-block exclusive scan (1024 elems/block, in place) + block totals
__global__ __launch_bounds__(256) void scan1_kernel(int* __restrict__ data,
                                                    int* __restrict__ partials,
                                                    int N) {
  __shared__ int wsum[4];
  int t = threadIdx.x;
  int base = blockIdx.x * 1024 + t * 4;
  int v0 = (base + 0 < N) ? data[base + 0] : 0;
  int v1 = (base + 1 < N) ? data[base + 1] : 0;
  int v2 = (base + 2 < N) ? data[base + 2] : 0;
  int v3 = (base + 3 < N) ? data[base + 3] : 0;
  int s = v0 + v1 + v2 + v3;
  int ps = s;
  int lane = t & 63;
#pragma unroll
  for (int off = 1; off < 64; off <<= 1) {
    int n = __shfl_up(ps, off, 64);
    if (lane >= off) ps += n;
  }
  if (lane == 63) wsum[t >> 6] = ps;
  __syncthreads();
  int woff = 0;
  for (int w = 0; w < (t >> 6); ++w) woff += wsum[w];
  int ex = woff + ps - s;
  if (base + 0 < N) data[base + 0] = ex;
  if (base + 1 < N) data[base + 1] = ex + v0;
  if (base + 2 < N) data[base + 2] = ex + v0 + v1;
  if (base + 3 < N) data[base + 3] = ex + v0 + v1 + v2;
  if (t == 255) partials[blockIdx.x] = woff + ps;
}

// 2b) exclusive scan of block totals (single block; nb <= 256)
__global__ __launch_bounds__(256) void scan2_kernel(int* __restrict__ partials,
                                                    int nb) {
  __shared__ int wsum[4];
  int t = threadIdx.x;
  int v = (t < nb) ? partials[t] : 0;
  int ps = v;
  int lane = t & 63;
#pragma unroll
  for (int off = 1; off < 64; off <<= 1) {
    int n = __shfl_up(ps, off, 64);
    if (lane >= off) ps += n;
  }
  if (lane == 63) wsum[t >> 6] = ps;
  __syncthreads();
  int woff = 0;
  for (int w = 0; w < (t >> 6); ++w) woff += wsum[w];
  if (t < nb) partials[t] = woff + ps - v;
}

// 2c) finalize region starts; copy to fill[]
__global__ __launch_bounds__(256) void scan3_kernel(
    int* __restrict__ rs, int* __restrict__ fill,
    const int* __restrict__ partials, int NC) {
  int i = blockIdx.x * 256 + threadIdx.x;
  if (i < NC) {
    int v = rs[i] + partials[i >> 10];
    rs[i] = v;
    fill[i] = v;
  }
}

// 3) bin-scatter: packed (col<<7 | row_local, val_bits) into region slots.
//    Positions within a region are time-sequential and single-XCD -> lines
//    assemble fully in that XCD's L2 before writeback.
__global__ __launch_bounds__(256) void bin_scatter_kernel(
    const int* __restrict__ erow, const int* __restrict__ ecol,
    const float* __restrict__ eval, int* __restrict__ fill,
    uint2* __restrict__ binned, int E, int cpb) {
  int b = blockIdx.x;
  int xp = b & 7;
  int base = b * cpb;
  int end = min(E, base + cpb);
  for (int e = base + threadIdx.x; e < end; e += 256) {
    int r = erow[e];
    uint2 p;
    p.x = ((unsigned)ecol[e] << 7) | (unsigned)(r & 127);
    p.y = __float_as_uint(eval[e]);
    int pos = atomicAdd(&fill[(r >> 7) * 8 + xp], 1);
    binned[pos] = p;
  }
}

// 4) per-bucket fused SpMM (LDS agg) + Linear + LayerNorm + ReLU.
//    One block per bucket of 128 rows. 16-lane groups per edge.
__global__ __launch_bounds__(256) void bucket_spmm_fused(
    const float* __restrict__ x, const uint2* __restrict__ binned,
    const int* __restrict__ rs, const int* __restrict__ fill,
    const float* __restrict__ W, const float* __restrict__ bias,
    const float* __restrict__ gamma, const float* __restrict__ beta,
    float* __restrict__ out, int N) {
  __shared__ float agg[RPB * DIM];   // 32 KB
  __shared__ float Wt[64 * 65];      // 16.6 KB

  const int t = threadIdx.x;
  const int bucket = blockIdx.x;

  for (int i = t; i < RPB * DIM; i += 256) agg[i] = 0.0f;
  for (int i = t; i < 64 * 64; i += 256) {
    int d = i >> 6, k = i & 63;
    Wt[k * 65 + d] = W[i];
  }
  __syncthreads();

  const int grp = t >> 4;   // 16 groups of 16 lanes
  const int lid = t & 15;

#pragma unroll 1
  for (int xp = 0; xp < 8; ++xp) {
    int idx = bucket * 8 + xp;
    int s = rs[idx];
    int en = fill[idx];
    for (int e = s + grp; e < en; e += 16) {
      uint2 p = binned[e];
      int col = (int)(p.x >> 7);
      int rl = (int)(p.x & 127);
      float v = __uint_as_float(p.y);
      const float4 xv =
          *reinterpret_cast<const float4*>(x + (size_t)col * DIM + lid * 4);
      float* dst = &agg[rl * DIM + lid * 4];
      atomicAdd(dst + 0, v * xv.x);
      atomicAdd(dst + 1, v * xv.y);
      atomicAdd(dst + 2, v * xv.z);
      atomicAdd(dst + 3, v * xv.w);
    }
  }
  __syncthreads();

  // Epilogue: Linear + LN + ReLU straight out of LDS agg.
  const int wave = t >> 6;
  const int lane = t & 63;
  const float bv = bias[lane];
  const float gv = gamma[lane];
  const float btv = beta[lane];
  const int node_base = bucket * RPB;

#pragma unroll 1
  for (int it = 0; it < RPB / 16; ++it) {
    int r0 = it * 16 + wave * 4;
    float a0 = agg[(r0 + 0) * DIM + lane];
    float a1 = agg[(r0 + 1) * DIM + lane];
    float a2 = agg[(r0 + 2) * DIM + lane];
    float a3 = agg[(r0 + 3) * DIM + lane];

    float acc0 = 0.f, acc1 = 0.f, acc2 = 0.f, acc3 = 0.f;
#pragma unroll
    for (int k = 0; k < 64; ++k) {
      float w = Wt[k * 65 + lane];
      acc0 = fmaf(readlane_f(a0, k), w, acc0);
      acc1 = fmaf(readlane_f(a1, k), w, acc1);
      acc2 = fmaf(readlane_f(a2, k), w, acc2);
      acc3 = fmaf(readlane_f(a3, k), w, acc3);
    }

    float accs[4] = {acc0, acc1, acc2, acc3};
#pragma unroll
    for (int j = 0; j < 4; ++j) {
      int node = node_base + r0 + j;
      if (node >= N) continue;
      float h = accs[j] + bv;
      float s1 = h, s2 = h * h;
#pragma unroll
      for (int off = 32; off; off >>= 1) {
        s1 += __shfl_xor(s1, off, 64);
        s2 += __shfl_xor(s2, off, 64);
      }
      float mu = s1 * (1.0f / 64.0f);
      float var = s2 * (1.0f / 64.0f) - mu * mu;
      float inv = rsqrtf(var + 1e-5f);
      float y = (h - mu) * inv * gv + btv;
      out[(size_t)node * DIM + lane] = fmaxf(y, 0.0f);
    }
  }
}

// ===========================================================================
extern "C" void kernel_launch(void* const* d_in, const int* in_sizes, int n_in,
                              void* d_out, int out_size, void* d_ws,
                              size_t ws_size, hipStream_t stream) {
  const float* x = (const float*)d_in[0];
  const int* erow = (const int*)d_in[1];
  const int* ecol = (const int*)d_in[2];
  const float* eval = (const float*)d_in[3];
  const float* W = (const float*)d_in[4];
  const float* bias = (const float*)d_in[5];
  const float* gamma = (const float*)d_in[6];
  const float* beta = (const float*)d_in[7];
  float* out = (float*)d_out;

  const int N = in_sizes[0] / DIM;
  const int E = in_sizes[1];

  const int NB = (N + RPB - 1) / RPB;       // buckets
  const int NC = NB * 8;                    // (bucket, xcd-part) regions
  const int nblk_scan = (NC + 1023) / 1024;

  size_t int_words = (size_t)NC * 2 + 256;  // rs + fill + partials
  size_t binned_off = ((int_words * sizeof(int)) + 15) & ~(size_t)15;
  size_t need = binned_off + (size_t)E * sizeof(uint2);

  if (ws_size >= need && nblk_scan <= 256 && N <= (1 << 25)) {
    int* rs = (int*)d_ws;                   // NC
    int* fill = rs + NC;                    // NC
    int* partials = fill + NC;              // 256
    uint2* binned = (uint2*)((char*)d_ws + binned_off);  // E

    const int cpb = (E + NBLK1 - 1) / NBLK1;

    hipMemsetAsync(rs, 0, (size_t)NC * sizeof(int), stream);
    hist_bucket_kernel<<<NBLK1, 256, 0, stream>>>(erow, rs, E, cpb);
    scan1_kernel<<<nblk_scan, 256, 0, stream>>>(rs, partials, NC);
    scan2_kernel<<<1, 256, 0, stream>>>(partials, nblk_scan);
    scan3_kernel<<<(NC + 255) / 256, 256, 0, stream>>>(rs, fill, partials, NC);
    bin_scatter_kernel<<<NBLK1, 256, 0, stream>>>(erow, ecol, eval, fill,
                                                  binned, E, cpb);
    bucket_spmm_fused<<<NB, 256, 0, stream>>>(x, binned, rs, fill, W, bias,
                                              gamma, beta, out, N);
  } else {
    const size_t agg_bytes = (size_t)N * DIM * sizeof(float);
    float* agg = (ws_size >= agg_bytes) ? (float*)d_ws : out;
    hipMemsetAsync(agg, 0, agg_bytes, stream);
    long long total = (long long)E * 16;
    int blocks = (int)((total + 255) / 256);
    scatter_kernel<<<blocks, 256, 0, stream>>>(x, erow, ecol, eval, agg, E);
    fused_linear_ln_relu<<<(N + 15) / 16, 256, 0, stream>>>(agg, W, bias,
                                                            gamma, beta, out, N);
  }
}

// Round 5
// 141.954 us; speedup vs baseline: 6.2255x; 6.2255x over previous
//
#include <hip/hip_runtime.h>

#define DIM 64
#define RPB 128          // rows per bucket
#define NCHUNK 256       // edge chunks (and blocks) for count/scatter passes
#define MAXBUK 1024      // max buckets supported by LDS counters

__device__ __forceinline__ float readlane_f(float v, int l) {
  return __uint_as_float(__builtin_amdgcn_readlane(__float_as_uint(v), l));
}

// XCD-contiguous chunk mapping: XCD k (blockIdx%8) handles contiguous chunks.
__device__ __forceinline__ int chunk_id(int blk) {
  return (blk & 7) * (NCHUNK / 8) + (blk >> 3);
}

// ===========================================================================
// Fallback path (tiny workspace): atomic scatter + fused linear/LN/ReLU
// ===========================================================================
__global__ __launch_bounds__(256) void scatter_kernel(
    const float* __restrict__ x, const int* __restrict__ erow,
    const int* __restrict__ ecol, const float* __restrict__ eval,
    float* __restrict__ agg, int E) {
  int t = blockIdx.x * 256 + threadIdx.x;
  int e = t >> 4;
  if (e >= E) return;
  int lid = t & 15;
  int r = erow[e];
  int c = ecol[e];
  float v = eval[e];
  const float4 xv =
      *reinterpret_cast<const float4*>(x + (size_t)c * DIM + lid * 4);
  float* dst = agg + (size_t)r * DIM + lid * 4;
  atomicAdd(dst + 0, v * xv.x);
  atomicAdd(dst + 1, v * xv.y);
  atomicAdd(dst + 2, v * xv.z);
  atomicAdd(dst + 3, v * xv.w);
}

__global__ __launch_bounds__(256) void fused_linear_ln_relu(
    const float* __restrict__ agg, const float* __restrict__ W,
    const float* __restrict__ bias, const float* __restrict__ gamma,
    const float* __restrict__ beta, float* __restrict__ out, int N) {
  __shared__ float Wt[64 * 65];
  for (int i = threadIdx.x; i < 64 * 64; i += 256) {
    int d = i >> 6, k = i & 63;
    Wt[k * 65 + d] = W[i];
  }
  __syncthreads();

  const int wave = threadIdx.x >> 6;
  const int lane = threadIdx.x & 63;
  const int node0 = blockIdx.x * 16 + wave * 4;

  float a0 = 0.f, a1 = 0.f, a2 = 0.f, a3 = 0.f;
  if (node0 + 0 < N) a0 = agg[(size_t)(node0 + 0) * DIM + lane];
  if (node0 + 1 < N) a1 = agg[(size_t)(node0 + 1) * DIM + lane];
  if (node0 + 2 < N) a2 = agg[(size_t)(node0 + 2) * DIM + lane];
  if (node0 + 3 < N) a3 = agg[(size_t)(node0 + 3) * DIM + lane];

  float acc0 = 0.f, acc1 = 0.f, acc2 = 0.f, acc3 = 0.f;
#pragma unroll
  for (int k = 0; k < 64; ++k) {
    float w = Wt[k * 65 + lane];
    acc0 = fmaf(readlane_f(a0, k), w, acc0);
    acc1 = fmaf(readlane_f(a1, k), w, acc1);
    acc2 = fmaf(readlane_f(a2, k), w, acc2);
    acc3 = fmaf(readlane_f(a3, k), w, acc3);
  }

  const float bv = bias[lane];
  const float gv = gamma[lane];
  const float btv = beta[lane];
  float accs[4] = {acc0, acc1, acc2, acc3};
#pragma unroll
  for (int j = 0; j < 4; ++j) {
    int node = node0 + j;
    if (node >= N) continue;
    float h = accs[j] + bv;
    float s1 = h, s2 = h * h;
#pragma unroll
    for (int off = 32; off; off >>= 1) {
      s1 += __shfl_xor(s1, off, 64);
      s2 += __shfl_xor(s2, off, 64);
    }
    float mu = s1 * (1.0f / 64.0f);
    float var = s2 * (1.0f / 64.0f) - mu * mu;
    float inv = rsqrtf(var + 1e-5f);
    float y = (h - mu) * inv * gv + btv;
    out[(size_t)node * DIM + lane] = fmaxf(y, 0.0f);
  }
}

// ===========================================================================
// Two-level deterministic-position sort
// ===========================================================================

// 1) per-chunk bucket histogram via LDS counters -> counts[bucket*NCHUNK+cid]
__global__ __launch_bounds__(256) void count_coarse(
    const int* __restrict__ erow, int* __restrict__ counts, int E, int cpb,
    int NB) {
  __shared__ int cnt[MAXBUK];
  for (int i = threadIdx.x; i < NB; i += 256) cnt[i] = 0;
  __syncthreads();
  const int cid = chunk_id(blockIdx.x);
  const int base = cid * cpb;
  const int end = min(E, base + cpb);
  for (int e = base + threadIdx.x; e < end; e += 256)
    atomicAdd(&cnt[erow[e] >> 7], 1);
  __syncthreads();
  for (int i = threadIdx.x; i < NB; i += 256)
    counts[i * NCHUNK + cid] = cnt[i];
}

// 2a) per-block exclusive scan, 2048 elems/block (8 per thread)
__global__ __launch_bounds__(256) void scan1b_kernel(int* __restrict__ data,
                                                     int* __restrict__ partials,
                                                     int n) {
  __shared__ int wsum[4];
  const int t = threadIdx.x;
  const int base = blockIdx.x * 2048 + t * 8;
  int v[8];
  int s = 0;
#pragma unroll
  for (int j = 0; j < 8; ++j) {
    v[j] = (base + j < n) ? data[base + j] : 0;
    s += v[j];
  }
  int ps = s;
  const int lane = t & 63;
#pragma unroll
  for (int off = 1; off < 64; off <<= 1) {
    int nn = __shfl_up(ps, off, 64);
    if (lane >= off) ps += nn;
  }
  if (lane == 63) wsum[t >> 6] = ps;
  __syncthreads();
  int woff = 0;
  for (int w = 0; w < (t >> 6); ++w) woff += wsum[w];
  int ex = woff + ps - s;
#pragma unroll
  for (int j = 0; j < 8; ++j) {
    if (base + j < n) data[base + j] = ex;
    ex += v[j];
  }
  if (t == 255) partials[blockIdx.x] = woff + ps;
}

// 2b) exclusive scan of block totals (single block; nb <= 256)
__global__ __launch_bounds__(256) void scan2_kernel(int* __restrict__ partials,
                                                    int nb) {
  __shared__ int wsum[4];
  int t = threadIdx.x;
  int v = (t < nb) ? partials[t] : 0;
  int ps = v;
  int lane = t & 63;
#pragma unroll
  for (int off = 1; off < 64; off <<= 1) {
    int n = __shfl_up(ps, off, 64);
    if (lane >= off) ps += n;
  }
  if (lane == 63) wsum[t >> 6] = ps;
  __syncthreads();
  int woff = 0;
  for (int w = 0; w < (t >> 6); ++w) woff += wsum[w];
  if (t < nb) partials[t] = woff + ps - v;
}

// 2c) finalize scanned counts; extract bucket bases
__global__ __launch_bounds__(256) void scan3b_kernel(
    int* __restrict__ data, const int* __restrict__ partials,
    int* __restrict__ bucket_base, int NC, int NB, int E) {
  int i = blockIdx.x * 256 + threadIdx.x;
  if (i < NC) {
    int v = data[i] + partials[i >> 11];
    data[i] = v;
    if ((i & (NCHUNK - 1)) == 0) bucket_base[i / NCHUNK] = v;
  }
  if (i == 0) bucket_base[NB] = E;
}

// 3) coarse scatter: deterministic per-(bucket,chunk) contiguous ranges.
__global__ __launch_bounds__(256) void scatter_coarse(
    const int* __restrict__ erow, const int* __restrict__ ecol,
    const float* __restrict__ eval, const int* __restrict__ scanned,
    uint2* __restrict__ binned, int E, int cpb, int NB) {
  __shared__ int cur[MAXBUK];
  const int cid = chunk_id(blockIdx.x);
  for (int i = threadIdx.x; i < NB; i += 256)
    cur[i] = scanned[i * NCHUNK + cid];
  __syncthreads();
  const int base = cid * cpb;
  const int end = min(E, base + cpb);
  for (int e = base + threadIdx.x; e < end; e += 256) {
    int r = erow[e];
    uint2 p;
    p.x = ((unsigned)ecol[e] << 7) | (unsigned)(r & 127);
    p.y = __float_as_uint(eval[e]);
    int pos = atomicAdd(&cur[r >> 7], 1);
    binned[pos] = p;
  }
}

// 4) within-bucket exact CSR sort + row_start emission. One block per bucket;
//    all global reads/writes are contiguous within the bucket's range.
__global__ __launch_bounds__(256) void sort_fine(
    const uint2* __restrict__ binned, const int* __restrict__ bucket_base,
    uint2* __restrict__ csr, int* __restrict__ row_start, int N, int E) {
  __shared__ int hist[RPB];
  __shared__ int cursor[RPB];
  const int b = blockIdx.x;
  const int s = bucket_base[b];
  const int en = bucket_base[b + 1];
  const int t = threadIdx.x;
  if (t < RPB) hist[t] = 0;
  __syncthreads();
  for (int e = s + t; e < en; e += 256)
    atomicAdd(&hist[binned[e].x & 127], 1);
  __syncthreads();
  if (t == 0) {
    int run = 0;
    for (int i = 0; i < RPB; ++i) {
      int c = hist[i];
      cursor[i] = run;
      run += c;
    }
  }
  __syncthreads();
  if (t < RPB) {
    int node = b * RPB + t;
    if (node < N) row_start[node] = s + cursor[t];
  }
  if (b == 0 && t == 0) row_start[N] = E;
  __syncthreads();
  for (int e = s + t; e < en; e += 256) {
    uint2 p = binned[e];
    int rl = (int)(p.x & 127);
    int pos = s + atomicAdd(&cursor[rl], 1);
    uint2 q;
    q.x = p.x >> 7;  // col
    q.y = p.y;       // val bits
    csr[pos] = q;
  }
}

// 5) fused gather (SpMM, ILP-8 batches) + Linear + LayerNorm + ReLU.
__global__ __launch_bounds__(256) void fused_gather_linear_ln(
    const float* __restrict__ x, const uint2* __restrict__ csr,
    const int* __restrict__ row_start, const float* __restrict__ W,
    const float* __restrict__ bias, const float* __restrict__ gamma,
    const float* __restrict__ beta, float* __restrict__ out, int N) {
  __shared__ float Wt[64 * 65];
  __shared__ float xch[4][256];
  for (int i = threadIdx.x; i < 64 * 64; i += 256) {
    int d = i >> 6, k = i & 63;
    Wt[k * 65 + d] = W[i];
  }

  const int wave = threadIdx.x >> 6;
  const int lane = threadIdx.x & 63;
  const int grp = lane >> 4;
  const int lid = lane & 15;
  const int node0 = blockIdx.x * 16 + wave * 4;
  const int node = node0 + grp;

  float4 acc = make_float4(0.f, 0.f, 0.f, 0.f);
  if (node < N) {
    int s = row_start[node];
    int en = row_start[node + 1];
    int j = s;
    // main loop: batches of 8 -> 8 independent csr loads, 8 independent
    // x-row gathers in flight.
    for (; j + 8 <= en; j += 8) {
      uint2 p[8];
#pragma unroll
      for (int i = 0; i < 8; ++i) p[i] = csr[j + i];
      float4 xv[8];
#pragma unroll
      for (int i = 0; i < 8; ++i)
        xv[i] = *reinterpret_cast<const float4*>(x + (size_t)p[i].x * DIM +
                                                 lid * 4);
#pragma unroll
      for (int i = 0; i < 8; ++i) {
        float v = __uint_as_float(p[i].y);
        acc.x = fmaf(v, xv[i].x, acc.x);
        acc.y = fmaf(v, xv[i].y, acc.y);
        acc.z = fmaf(v, xv[i].z, acc.z);
        acc.w = fmaf(v, xv[i].w, acc.w);
      }
    }
    for (; j < en; ++j) {
      uint2 p0 = csr[j];
      float v0 = __uint_as_float(p0.y);
      const float4 x0 =
          *reinterpret_cast<const float4*>(x + (size_t)p0.x * DIM + lid * 4);
      acc.x = fmaf(v0, x0.x, acc.x);
      acc.y = fmaf(v0, x0.y, acc.y);
      acc.z = fmaf(v0, x0.z, acc.z);
      acc.w = fmaf(v0, x0.w, acc.w);
    }
  }
  __syncthreads();  // covers Wt staging too
  *reinterpret_cast<float4*>(&xch[wave][grp * 64 + lid * 4]) = acc;
  __syncthreads();

  float a0 = xch[wave][0 * 64 + lane];
  float a1 = xch[wave][1 * 64 + lane];
  float a2 = xch[wave][2 * 64 + lane];
  float a3 = xch[wave][3 * 64 + lane];

  float acc0 = 0.f, acc1 = 0.f, acc2 = 0.f, acc3 = 0.f;
#pragma unroll
  for (int k = 0; k < 64; ++k) {
    float w = Wt[k * 65 + lane];
    acc0 = fmaf(readlane_f(a0, k), w, acc0);
    acc1 = fmaf(readlane_f(a1, k), w, acc1);
    acc2 = fmaf(readlane_f(a2, k), w, acc2);
    acc3 = fmaf(readlane_f(a3, k), w, acc3);
  }

  const float bv = bias[lane];
  const float gv = gamma[lane];
  const float btv = beta[lane];
  float accs[4] = {acc0, acc1, acc2, acc3};
#pragma unroll
  for (int jj = 0; jj < 4; ++jj) {
    int nd = node0 + jj;
    if (nd >= N) continue;
    float h = accs[jj] + bv;
    float s1 = h, s2 = h * h;
#pragma unroll
    for (int off = 32; off; off >>= 1) {
      s1 += __shfl_xor(s1, off, 64);
      s2 += __shfl_xor(s2, off, 64);
    }
    float mu = s1 * (1.0f / 64.0f);
    float var = s2 * (1.0f / 64.0f) - mu * mu;
    float inv = rsqrtf(var + 1e-5f);
    float y = (h - mu) * inv * gv + btv;
    out[(size_t)nd * DIM + lane] = fmaxf(y, 0.0f);
  }
}

// ===========================================================================
extern "C" void kernel_launch(void* const* d_in, const int* in_sizes, int n_in,
                              void* d_out, int out_size, void* d_ws,
                              size_t ws_size, hipStream_t stream) {
  const float* x = (const float*)d_in[0];
  const int* erow = (const int*)d_in[1];
  const int* ecol = (const int*)d_in[2];
  const float* eval = (const float*)d_in[3];
  const float* W = (const float*)d_in[4];
  const float* bias = (const float*)d_in[5];
  const float* gamma = (const float*)d_in[6];
  const float* beta = (const float*)d_in[7];
  float* out = (float*)d_out;

  const int N = in_sizes[0] / DIM;
  const int E = in_sizes[1];

  const int NB = (N + RPB - 1) / RPB;   // row buckets
  const int NC = NB * NCHUNK;           // (bucket, chunk) counters
  const int nblk_scan = (NC + 2047) / 2048;
  const int cpb = (E + NCHUNK - 1) / NCHUNK;

  // ws layout: counts[NC] | partials[256] | bucket_base[NB+1] |
  //            row_start[N+1] | pad | binned[E] u2 | csr[E] u2
  size_t int_words = (size_t)NC + 256 + (NB + 1) + (N + 1);
  size_t u2_off = ((int_words * sizeof(int)) + 15) & ~(size_t)15;
  size_t need = u2_off + 2 * (size_t)E * sizeof(uint2);

  if (ws_size >= need && NB <= MAXBUK && nblk_scan <= 256) {
    int* counts = (int*)d_ws;                       // NC
    int* partials = counts + NC;                    // 256
    int* bucket_base = partials + 256;              // NB+1
    int* row_start = bucket_base + (NB + 1);        // N+1
    uint2* binned = (uint2*)((char*)d_ws + u2_off); // E
    uint2* csr = binned + E;                        // E

    hipMemsetAsync(counts, 0, (size_t)NC * sizeof(int), stream);
    count_coarse<<<NCHUNK, 256, 0, stream>>>(erow, counts, E, cpb, NB);
    scan1b_kernel<<<nblk_scan, 256, 0, stream>>>(counts, partials, NC);
    scan2_kernel<<<1, 256, 0, stream>>>(partials, nblk_scan);
    scan3b_kernel<<<(NC + 255) / 256, 256, 0, stream>>>(counts, partials,
                                                        bucket_base, NC, NB, E);
    scatter_coarse<<<NCHUNK, 256, 0, stream>>>(erow, ecol, eval, counts,
                                               binned, E, cpb, NB);
    sort_fine<<<NB, 256, 0, stream>>>(binned, bucket_base, csr, row_start, N,
                                      E);
    fused_gather_linear_ln<<<(N + 15) / 16, 256, 0, stream>>>(
        x, csr, row_start, W, bias, gamma, beta, out, N);
  } else {
    const size_t agg_bytes = (size_t)N * DIM * sizeof(float);
    float* agg = (ws_size >= agg_bytes) ? (float*)d_ws : out;
    hipMemsetAsync(agg, 0, agg_bytes, stream);
    long long total = (long long)E * 16;
    int blocks = (int)((total + 255) / 256);
    scatter_kernel<<<blocks, 256, 0, stream>>>(x, erow, ecol, eval, agg, E);
    fused_linear_ln_relu<<<(N + 15) / 16, 256, 0, stream>>>(agg, W, bias,
                                                            gamma, beta, out, N);
  }
}